// Round 9
// baseline (398.452 us; speedup 1.0000x reference)
//
#include <hip/hip_runtime.h>
#include <math.h>

#define NROWS   (64 * 4096)                 // 262144 rows
#define D       64
#define K       1024
#define NELEM   ((size_t)NROWS * (size_t)D) // 16777216

// ---- MFMA-path geometry (hi-only screening, codes pre-scaled by -2) ----
#define CHUNK_CODES 128
#define ROWB        144                       // padded code row bytes (64 bf16 = 128B + 16B pad)
#define NRM_OFF     (CHUNK_CODES * ROWB)      // 18432
#define REC_BYTES   20480                     // record stride = LDS buffer size
#define NCHUNK      (K / CHUNK_CODES)         // 8
#define WS_CHUNK_OFF 16384
#define WS_MAIN_NEED (WS_CHUNK_OFF + NCHUNK * REC_BYTES)   // 180224
#define BLK_ROWS    256                       // rows per block (4 waves x 64 rows)
#define NBLOCKS     (NROWS / BLK_ROWS)        // 1024

#define MBIAS  256.0f     // m = dist^2 - ||z||^2 + 256 > 0 always
// GAP_Q=0.8: screen err sigma ~0.08 -> ~9 sigma incl. 0.0625 key quantization.
// 0.4 (R6) produced absmax 5.3 = real argmin flips. 0.8 verified clean R3/R5/R7/R8.
#define GAP_Q  0.8f

typedef float  f32x4  __attribute__((ext_vector_type(4)));
typedef short  s16x8  __attribute__((ext_vector_type(8)));

// ws layout (main path, bytes):
// [0,4096)        uint counts[1024]   (zeroed per call)
// [4096,8192)     float block_loss[1024]
// [16384,+8*20480) chunk records: {hi(-2x) 128x144B | nrm+MBIAS 128xf32 | pad}
// fallback path:  [12288,16384) float norms[1024]

static __device__ inline unsigned bf16_rne(unsigned u) {
  return (u + 0x7FFFu + ((u >> 16) & 1u)) >> 16;
}
static __device__ inline unsigned umin_(unsigned a, unsigned b) { return a < b ? a : b; }
static __device__ inline unsigned umax_(unsigned a, unsigned b) { return a > b ? a : b; }

// ---------------- prep: codebook -> bf16(-2x) chunk records + biased norms -------------
__global__ __launch_bounds__(256) void vq_prep(const float* __restrict__ cb,
                                               char* __restrict__ ws) {
  int k = blockIdx.x * 256 + threadIdx.x;
  if (k >= K) return;
  int chunk = k >> 7, cc = k & 127;
  char* rec = ws + WS_CHUNK_OFF + chunk * REC_BYTES;
  unsigned short* hrow = (unsigned short*)(rec + cc * ROWB);
  const float* src = cb + (k << 6);
  float nrm = 0.f;
  for (int j = 0; j < 64; j += 2) {
    float x0 = src[j], x1 = src[j + 1];
    nrm = fmaf(x0, x0, fmaf(x1, x1, nrm));
    unsigned h0 = bf16_rne(__float_as_uint(-2.f * x0));   // -2x exact in bf16
    unsigned h1 = bf16_rne(__float_as_uint(-2.f * x1));
    *(unsigned*)(hrow + j) = h0 | (h1 << 16);
  }
  *(float*)(rec + NRM_OFF + cc * 4) = nrm + MBIAS;
}

// ---------------- main MFMA kernel -------------
// (256,2): 256-VGPR cap. Body needs ~100 regs (4 row-tiles + split trackers);
// (256,4)'s 64-reg choice caused marginal spill in R6 (WRITE 81 vs 73 MB).
// Occupancy is empirically pinned at ~10 waves/CU regardless (R5-R8), so
// per-wave ILP, not wave count, is the lever.
__global__ __launch_bounds__(256, 2) void vq_mfma(const float* __restrict__ z,
                                                  const float* __restrict__ cb,
                                                  const char* __restrict__ ws,
                                                  float* __restrict__ zq,
                                                  unsigned int* __restrict__ counts,
                                                  float* __restrict__ block_loss) {
  __shared__ __align__(16) char sblob[REC_BYTES];   // 20 KB single buffer

  const int t    = threadIdx.x;
  const int w    = t >> 6;          // wave 0..3
  const int lane = t & 63;
  const int g    = lane >> 4;       // k-group 0..3
  const int ln16 = lane & 15;

  // ---- load z rows (4 row-tiles x 16 rows), bf16 B-frags ----
  // lane holds z[row = rowbase + rt*16 + ln16][k = ks*32 + g*8 + j], j=0..7
  const int rowbase = blockIdx.x * BLK_ROWS + w * 64;
  s16x8 zh[4][2];
#pragma unroll
  for (int rt = 0; rt < 4; ++rt) {
    int row = rowbase + rt * 16 + ln16;
    const float4* zr = (const float4*)(z + (size_t)row * 64);
#pragma unroll
    for (int ks = 0; ks < 2; ++ks) {
      float4 a = zr[ks * 8 + g * 2];
      float4 b = zr[ks * 8 + g * 2 + 1];
      s16x8 hh;
      hh[0] = (short)bf16_rne(__float_as_uint(a.x));
      hh[1] = (short)bf16_rne(__float_as_uint(a.y));
      hh[2] = (short)bf16_rne(__float_as_uint(a.z));
      hh[3] = (short)bf16_rne(__float_as_uint(a.w));
      hh[4] = (short)bf16_rne(__float_as_uint(b.x));
      hh[5] = (short)bf16_rne(__float_as_uint(b.y));
      hh[6] = (short)bf16_rne(__float_as_uint(b.z));
      hh[7] = (short)bf16_rne(__float_as_uint(b.w));
      zh[rt][ks] = hh;
    }
  }

  // packed-key top-3, TWO independent trackers per row-tile (A: R<2, B: R>=2)
  // -> halves the serial min/max chain per tile. Merged after the k-loop.
  unsigned qa1[4] = {~0u, ~0u, ~0u, ~0u}, qa2[4] = {~0u, ~0u, ~0u, ~0u}, qa3[4] = {~0u, ~0u, ~0u, ~0u};
  unsigned qb1[4] = {~0u, ~0u, ~0u, ~0u}, qb2[4] = {~0u, ~0u, ~0u, ~0u}, qb3[4] = {~0u, ~0u, ~0u, ~0u};

  const int aoff = ln16 * ROWB + g * 16;      // A-frag byte offset within code rows

#define LD_TILE(TL, E0, E1, NR) {                                             \
    const char* _ab = sblob + (TL) * (16 * ROWB) + aoff;                      \
    E0 = *(const s16x8*)(_ab);                                                \
    E1 = *(const s16x8*)(_ab + 64);                                           \
    NR = *(const f32x4*)(sblob + NRM_OFF + (TL) * 64 + (g << 4)); }

  const float4* wsrc = (const float4*)(ws + WS_CHUNK_OFF);

  for (int c = 0; c < NCHUNK; ++c) {
    __syncthreads();   // previous chunk fully consumed
    {
      const float4* src = wsrc + (size_t)c * (REC_BYTES / 16);
      float4* dst = (float4*)sblob;
#pragma unroll
      for (int i = 0; i < 5; ++i) {     // 256*5*16B = 20480B, unconditional
        int idx = t + 256 * i;
        dst[idx] = src[idx];
      }
    }
    __syncthreads();

    // register double-buffer of ds_reads: tile tl+1 issues before tile tl retires
    s16x8 e0a, e1a; f32x4 nra;
    LD_TILE(0, e0a, e1a, nra)
#pragma unroll
    for (int tl = 0; tl < 8; ++tl) {
      s16x8 e0b, e1b; f32x4 nrb;
      if (tl < 7) { LD_TILE(tl + 1, e0b, e1b, nrb) }

      // acc init = biased norm; codes are -2x, so acc ends as m = nrm+MBIAS-2*dot
      f32x4 ac0 = nra, ac1 = nra, ac2 = nra, ac3 = nra;
      ac0 = __builtin_amdgcn_mfma_f32_16x16x32_bf16(e0a, zh[0][0], ac0, 0, 0, 0);
      ac1 = __builtin_amdgcn_mfma_f32_16x16x32_bf16(e0a, zh[1][0], ac1, 0, 0, 0);
      ac2 = __builtin_amdgcn_mfma_f32_16x16x32_bf16(e0a, zh[2][0], ac2, 0, 0, 0);
      ac3 = __builtin_amdgcn_mfma_f32_16x16x32_bf16(e0a, zh[3][0], ac3, 0, 0, 0);
      ac0 = __builtin_amdgcn_mfma_f32_16x16x32_bf16(e1a, zh[0][1], ac0, 0, 0, 0);
      ac1 = __builtin_amdgcn_mfma_f32_16x16x32_bf16(e1a, zh[1][1], ac1, 0, 0, 0);
      ac2 = __builtin_amdgcn_mfma_f32_16x16x32_bf16(e1a, zh[2][1], ac2, 0, 0, 0);
      ac3 = __builtin_amdgcn_mfma_f32_16x16x32_bf16(e1a, zh[3][1], ac3, 0, 0, 0);

      const unsigned kb = (unsigned)((c << 7) + (tl << 4) + (g << 2));
#define UPDP(Q1, Q2, Q3, RT, R) {                                             \
        unsigned key = (__float_as_uint(ac##RT[R]) & 0xFFFFFC00u) | (kb + R); \
        unsigned t1 = umax_(Q1[RT], key); Q1[RT] = umin_(Q1[RT], key);        \
        unsigned t2 = umax_(Q2[RT], t1);  Q2[RT] = umin_(Q2[RT], t1);         \
        Q3[RT] = umin_(Q3[RT], t2); }
      // R 0,1 -> tracker A;  R 2,3 -> tracker B (independent chains)
      UPDP(qa1, qa2, qa3, 0, 0) UPDP(qa1, qa2, qa3, 1, 0) UPDP(qa1, qa2, qa3, 2, 0) UPDP(qa1, qa2, qa3, 3, 0)
      UPDP(qb1, qb2, qb3, 0, 2) UPDP(qb1, qb2, qb3, 1, 2) UPDP(qb1, qb2, qb3, 2, 2) UPDP(qb1, qb2, qb3, 3, 2)
      UPDP(qa1, qa2, qa3, 0, 1) UPDP(qa1, qa2, qa3, 1, 1) UPDP(qa1, qa2, qa3, 2, 1) UPDP(qa1, qa2, qa3, 3, 1)
      UPDP(qb1, qb2, qb3, 0, 3) UPDP(qb1, qb2, qb3, 1, 3) UPDP(qb1, qb2, qb3, 2, 3) UPDP(qb1, qb2, qb3, 3, 3)
#undef UPDP
      if (tl < 7) { e0a = e0b; e1a = e1b; nra = nrb; }
    }
  }

  __syncthreads();                    // all waves done reading sblob codes
  int*   sk  = (int*)sblob;           // [256] overlaid
  float* red = (float*)(sblob + 1024);// [256] overlaid

  const float4* cb4 = (const float4*)cb;
  const float4* z4g = (const float4*)z;

#pragma unroll
  for (int rt = 0; rt < 4; ++rt) {
    // merge tracker A and B sorted triples (in-register), then across lanes
    unsigned a1 = qa1[rt], a2 = qa2[rt], a3 = qa3[rt];
    {
      unsigned b1 = qb1[rt], b2 = qb2[rt], b3 = qb3[rt];
      unsigned x  = umax_(a1, b1);
      a1 = umin_(a1, b1);
      unsigned y  = umin_(a2, b2);
      unsigned zz = umax_(a2, b2);
      unsigned w3 = umin_(a3, b3);
      a2 = umin_(x, y);
      a3 = umin_(umax_(x, y), umin_(zz, w3));
    }
#pragma unroll
    for (int dx = 16; dx <= 32; dx <<= 1) {
      unsigned b1 = (unsigned)__shfl_xor((int)a1, dx);
      unsigned b2 = (unsigned)__shfl_xor((int)a2, dx);
      unsigned b3 = (unsigned)__shfl_xor((int)a3, dx);
      unsigned x  = umax_(a1, b1);
      a1 = umin_(a1, b1);
      unsigned y  = umin_(a2, b2);
      unsigned zz = umax_(a2, b2);
      unsigned w3 = umin_(a3, b3);
      a2 = umin_(x, y);
      a3 = umin_(umax_(x, y), umin_(zz, w3));
    }
    int   i1 = (int)(a1 & 1023u), i2 = (int)(a2 & 1023u);
    float f1 = __uint_as_float(a1 & 0xFFFFFC00u);
    float f2 = __uint_as_float(a2 & 0xFFFFFC00u);
    float f3 = __uint_as_float(a3 & 0xFFFFFC00u);
    bool needFull = (f3 - f1) < GAP_Q;   // winner may lie outside {i1,i2}
    bool needPair = !needFull && ((f2 - f1) < GAP_Q);
    int  kstar = i1;

    if (g == 0) {
      int row = rowbase + rt * 16 + ln16;
      if (needPair) {
        float d1 = 0.f, d2 = 0.f;
        const float4* zr = z4g + (size_t)row * 16;
        const float4* c1 = cb4 + i1 * 16;
        const float4* c2 = cb4 + i2 * 16;
#pragma unroll
        for (int j = 0; j < 16; ++j) {
          float4 zv = zr[j], a = c1[j], b = c2[j];
          float e;
          e = zv.x - a.x; d1 = fmaf(e, e, d1);
          e = zv.y - a.y; d1 = fmaf(e, e, d1);
          e = zv.z - a.z; d1 = fmaf(e, e, d1);
          e = zv.w - a.w; d1 = fmaf(e, e, d1);
          e = zv.x - b.x; d2 = fmaf(e, e, d2);
          e = zv.y - b.y; d2 = fmaf(e, e, d2);
          e = zv.z - b.z; d2 = fmaf(e, e, d2);
          e = zv.w - b.w; d2 = fmaf(e, e, d2);
        }
        if (d2 < d1 || (d2 == d1 && i2 < i1)) kstar = i2;
      }
      if (!needFull) {
        sk[w * 64 + rt * 16 + ln16] = kstar;
        atomicAdd(&counts[kstar], 1u);
      }
    }

    // wave-cooperative exact full rescan for flagged rows (rare)
    unsigned long long fullmask = __ballot(needFull && g == 0);
    while (fullmask) {
      int src = __ffsll(fullmask) - 1;
      fullmask &= fullmask - 1;
      int lrow = w * 64 + rt * 16 + src;
      int row  = blockIdx.x * BLK_ROWS + lrow;
      const float4* zr = z4g + (size_t)row * 16;
      float bv = 3.4e38f; int bi = 0;
      for (int c16 = 0; c16 < 16; ++c16) {
        int code = c16 * 64 + lane;
        const float4* cr = cb4 + code * 16;
        float d = 0.f;
#pragma unroll
        for (int j = 0; j < 16; ++j) {
          float4 zv = zr[j], cv = cr[j];
          float e;
          e = zv.x - cv.x; d = fmaf(e, e, d);
          e = zv.y - cv.y; d = fmaf(e, e, d);
          e = zv.z - cv.z; d = fmaf(e, e, d);
          e = zv.w - cv.w; d = fmaf(e, e, d);
        }
        if (d < bv) { bv = d; bi = code; }
      }
#pragma unroll
      for (int dx = 1; dx < 64; dx <<= 1) {
        float ov = __shfl_xor(bv, dx); int oi = __shfl_xor(bi, dx);
        if (ov < bv || (ov == bv && oi < bi)) { bv = ov; bi = oi; }
      }
      if (lane == 0) { sk[lrow] = bi; atomicAdd(&counts[bi], 1u); }
    }
  }

  __syncthreads();

  // ---- cooperative z_q write + exact loss ----
  float lpart = 0.f;
  const int base4 = blockIdx.x * (BLK_ROWS * 16);
  float4* out4 = (float4*)zq;
#pragma unroll
  for (int i = 0; i < 16; ++i) {
    int idx = t + 256 * i;            // [0, 4096)
    int row = idx >> 4, c4 = idx & 15;
    int kk = sk[row];
    float4 cv = cb4[kk * 16 + c4];
    float4 zv = z4g[base4 + idx];
    float e;
    e = zv.x - cv.x; lpart = fmaf(e, e, lpart);
    e = zv.y - cv.y; lpart = fmaf(e, e, lpart);
    e = zv.z - cv.z; lpart = fmaf(e, e, lpart);
    e = zv.w - cv.w; lpart = fmaf(e, e, lpart);
    out4[base4 + idx] = cv;
  }
  red[t] = lpart;
  __syncthreads();
#pragma unroll
  for (int s = 128; s > 0; s >>= 1) {
    if (t < s) red[t] += red[t + s];
    __syncthreads();
  }
  if (t == 0) block_loss[blockIdx.x] = red[0];
}

// ---------------- finalize -------------
__global__ __launch_bounds__(1024) void vq_finalize(const unsigned int* __restrict__ counts,
                                                    const float* __restrict__ block_loss,
                                                    float* __restrict__ out, int nb) {
  __shared__ float sh[1024];
  __shared__ float sl[1024];
  const int t = threadIdx.x;
  float c = (float)counts[t];
  float p = c * (1.0f / (float)NROWS);
  sh[t] = p * logf(p + 1e-10f);
  float bl = (t < nb) ? block_loss[t] : 0.f;
  sl[t] = bl;
  __syncthreads();
#pragma unroll
  for (int s = 512; s > 0; s >>= 1) {
    if (t < s) { sh[t] += sh[t + s]; sl[t] += sl[t + s]; }
    __syncthreads();
  }
  if (t == 0) {
    out[NELEM]     = 1.25f * sl[0] / (float)NELEM;
    out[NELEM + 1] = expf(-sh[0]);
  }
}

// ---------------- fallback (small ws): fp32 kernel -------------
#define DOT4(acc, a, e) \
  acc = fmaf((a).x, (e).x, fmaf((a).y, (e).y, fmaf((a).z, (e).z, fmaf((a).w, (e).w, (acc)))))
#define SQD4(acc, a, e) { \
  float _dx = (e).x - (a).x, _dy = (e).y - (a).y, _dz = (e).z - (a).z, _dw = (e).w - (a).w; \
  acc = fmaf(_dx, _dx, fmaf(_dy, _dy, fmaf(_dz, _dz, fmaf(_dw, _dw, (acc))))); }

__global__ __launch_bounds__(256) void vq_norms_fb(const float* __restrict__ cb,
                                                   float* __restrict__ norms) {
  int k = blockIdx.x * blockDim.x + threadIdx.x;
  if (k >= K) return;
  const float4* e4 = (const float4*)(cb + (k << 6));
  float a0 = 0.f, a1 = 0.f, a2 = 0.f, a3 = 0.f;
#pragma unroll
  for (int j = 0; j < 16; j += 4) {
    float4 e;
    e = e4[j + 0]; DOT4(a0, e, e);
    e = e4[j + 1]; DOT4(a1, e, e);
    e = e4[j + 2]; DOT4(a2, e, e);
    e = e4[j + 3]; DOT4(a3, e, e);
  }
  norms[k] = (a0 + a1) + (a2 + a3);
}

__global__ __launch_bounds__(256) void vq_main_fb(const float* __restrict__ z,
                                                  const float* __restrict__ cb,
                                                  const float* __restrict__ norms,
                                                  float* __restrict__ zq,
                                                  unsigned int* __restrict__ counts,
                                                  float* __restrict__ block_loss) {
  const int tid = threadIdx.x;
  const int row = blockIdx.x * 256 + tid;
  const float4* zr4 = (const float4*)(z + (size_t)row * D);
  float4 zr[16];
#pragma unroll
  for (int j = 0; j < 16; ++j) zr[j] = zr4[j];
  float best = 3.4e38f;
  int   bidx = 0;
  for (int k = 0; k < K; k += 2) {
    const float4* e0 = (const float4*)(cb + (k << 6));
    const float4* e1 = e0 + 16;
    float a0 = 0.f, a1 = 0.f, a2 = 0.f, a3 = 0.f;
    float b0 = 0.f, b1 = 0.f, b2 = 0.f, b3 = 0.f;
#pragma unroll
    for (int j = 0; j < 16; j += 4) {
      float4 tt;
      tt = e0[j + 0]; DOT4(a0, zr[j + 0], tt);
      tt = e1[j + 0]; DOT4(b0, zr[j + 0], tt);
      tt = e0[j + 1]; DOT4(a1, zr[j + 1], tt);
      tt = e1[j + 1]; DOT4(b1, zr[j + 1], tt);
      tt = e0[j + 2]; DOT4(a2, zr[j + 2], tt);
      tt = e1[j + 2]; DOT4(b2, zr[j + 2], tt);
      tt = e0[j + 3]; DOT4(a3, zr[j + 3], tt);
      tt = e1[j + 3]; DOT4(b3, zr[j + 3], tt);
    }
    float d0 = (a0 + a1) + (a2 + a3);
    float d1 = (b0 + b1) + (b2 + b3);
    float m0 = fmaf(-2.f, d0, norms[k]);
    float m1 = fmaf(-2.f, d1, norms[k + 1]);
    if (m0 < best) { best = m0; bidx = k; }
    if (m1 < best) { best = m1; bidx = k + 1; }
  }
  const float4* eb4 = (const float4*)(cb + ((size_t)bidx << 6));
  float4* o4 = (float4*)(zq + (size_t)row * D);
  float l0 = 0.f, l1 = 0.f, l2 = 0.f, l3 = 0.f;
#pragma unroll
  for (int j = 0; j < 16; j += 4) {
    float4 e;
    e = eb4[j + 0]; o4[j + 0] = e; SQD4(l0, zr[j + 0], e);
    e = eb4[j + 1]; o4[j + 1] = e; SQD4(l1, zr[j + 1], e);
    e = eb4[j + 2]; o4[j + 2] = e; SQD4(l2, zr[j + 2], e);
    e = eb4[j + 3]; o4[j + 3] = e; SQD4(l3, zr[j + 3], e);
  }
  float row_loss = (l0 + l1) + (l2 + l3);
  atomicAdd(&counts[bidx], 1u);
  __shared__ float redf[256];
  redf[tid] = row_loss;
  __syncthreads();
#pragma unroll
  for (int s = 128; s > 0; s >>= 1) {
    if (tid < s) redf[tid] += redf[tid + s];
    __syncthreads();
  }
  if (tid == 0) block_loss[blockIdx.x] = redf[0];
}

// ---------------- launch -------------
extern "C" void kernel_launch(void* const* d_in, const int* in_sizes, int n_in,
                              void* d_out, int out_size, void* d_ws, size_t ws_size,
                              hipStream_t stream) {
  const float* z  = (const float*)d_in[0];
  const float* cb = (const float*)d_in[1];
  float* out = (float*)d_out;

  unsigned int* counts     = (unsigned int*)d_ws;
  float*        block_loss = (float*)((char*)d_ws + 4096);

  hipMemsetAsync(d_ws, 0, 4096, stream);   // zero counts

  if (ws_size >= WS_MAIN_NEED) {
    vq_prep<<<dim3(4), dim3(256), 0, stream>>>(cb, (char*)d_ws);
    vq_mfma<<<dim3(NBLOCKS), dim3(256), 0, stream>>>(z, cb, (const char*)d_ws,
                                                     out, counts, block_loss);
    vq_finalize<<<dim3(1), dim3(1024), 0, stream>>>(counts, block_loss, out, NBLOCKS);
  } else {
    float* norms = (float*)((char*)d_ws + 12288);
    vq_norms_fb<<<dim3(4), dim3(256), 0, stream>>>(cb, norms);
    vq_main_fb<<<dim3(NROWS / 256), dim3(256), 0, stream>>>(z, cb, norms,
                                                            out, counts, block_loss);
    vq_finalize<<<dim3(1), dim3(1024), 0, stream>>>(counts, block_loss, out, 1024);
  }
}

// Round 10
// 367.860 us; speedup vs baseline: 1.0832x; 1.0832x over previous
//
#include <hip/hip_runtime.h>
#include <math.h>

#define NROWS   (64 * 4096)                 // 262144 rows
#define D       64
#define K       1024
#define NELEM   ((size_t)NROWS * (size_t)D) // 16777216

// ---- MFMA-path geometry (hi-only screening, codes pre-scaled by -2) ----
#define ROWB        144                       // padded code row bytes (64 bf16 = 128B + 16B pad)
#define CODES_BYTES (K * ROWB)                // 147456 (single contiguous record)
#define WS_CHUNK_OFF 16384
#define WS_MAIN_NEED (WS_CHUNK_OFF + CODES_BYTES + K * 4)  // 167936
#define PH_CODES    256                       // codes per phase
#define PH_CBYTES   (PH_CODES * ROWB)         // 36864
#define LDS_NRM_OFF PH_CBYTES                 // norms after codes in LDS
#define LDS_BYTES   (PH_CBYTES + PH_CODES * 4)  // 37888
#define NPHASE      (K / PH_CODES)            // 4
#define BLK_ROWS    256                       // 4 waves x 64 rows
#define NBLOCKS     (NROWS / BLK_ROWS)        // 1024

#define MBIAS  256.0f     // m = dist^2 - ||z||^2 + 256 > 0 always
// GAP_Q=0.8: screen err sigma ~0.08 -> ~9 sigma incl. 0.0625 key quantization.
// 0.4 (R6) produced absmax 5.3 = real argmin flips. 0.8 verified clean R3/R5/R7/R8/R9.
#define GAP_Q  0.8f

typedef float  f32x4  __attribute__((ext_vector_type(4)));
typedef short  s16x8  __attribute__((ext_vector_type(8)));

// ws layout (main path, bytes):
// [0,4096)        uint counts[1024]   (zeroed per call)
// [4096,8192)     float block_loss[1024]
// [16384,+147456) codes: 1024 x 144B bf16(-2x)
// [+147456,+4096) norms+MBIAS: 1024 x f32
// fallback path:  [12288,16384) float norms[1024]

static __device__ inline unsigned bf16_rne(unsigned u) {
  return (u + 0x7FFFu + ((u >> 16) & 1u)) >> 16;
}
static __device__ inline unsigned umin_(unsigned a, unsigned b) { return a < b ? a : b; }
static __device__ inline unsigned umax_(unsigned a, unsigned b) { return a > b ? a : b; }

// ---------------- prep: codebook -> bf16(-2x) record + biased norms -------------
__global__ __launch_bounds__(256) void vq_prep(const float* __restrict__ cb,
                                               char* __restrict__ ws) {
  int k = blockIdx.x * 256 + threadIdx.x;
  if (k >= K) return;
  unsigned short* hrow = (unsigned short*)(ws + WS_CHUNK_OFF + k * ROWB);
  const float* src = cb + (k << 6);
  float nrm = 0.f;
  for (int j = 0; j < 64; j += 2) {
    float x0 = src[j], x1 = src[j + 1];
    nrm = fmaf(x0, x0, fmaf(x1, x1, nrm));
    unsigned h0 = bf16_rne(__float_as_uint(-2.f * x0));   // -2x exact in bf16
    unsigned h1 = bf16_rne(__float_as_uint(-2.f * x1));
    *(unsigned*)(hrow + j) = h0 | (h1 << 16);
  }
  *(float*)(ws + WS_CHUNK_OFF + CODES_BYTES + k * 4) = nrm + MBIAS;
}

// ---------------- main MFMA kernel -------------
// Fat iterations: 2 code-tiles (32 codes) per iter = 16 MFMA + ~128 VALU issue
// -> a single wave saturates the VALU pipe; latency hiding no longer relies on
// occupancy (empirically pinned at 2-3 waves/SIMD, R5-R9).
__global__ __launch_bounds__(256, 4) void vq_mfma(const float* __restrict__ z,
                                                  const float* __restrict__ cb,
                                                  const char* __restrict__ ws,
                                                  float* __restrict__ zq,
                                                  unsigned int* __restrict__ counts,
                                                  float* __restrict__ block_loss) {
  __shared__ __align__(16) char sblob[LDS_BYTES];   // 37 KB single buffer

  const int t    = threadIdx.x;
  const int w    = t >> 6;          // wave 0..3
  const int lane = t & 63;
  const int g    = lane >> 4;       // k-group 0..3
  const int ln16 = lane & 15;

  // ---- load z rows (4 row-tiles x 16 rows), bf16 B-frags ----
  const int rowbase = blockIdx.x * BLK_ROWS + w * 64;
  s16x8 zh[4][2];
#pragma unroll
  for (int rt = 0; rt < 4; ++rt) {
    int row = rowbase + rt * 16 + ln16;
    const float4* zr = (const float4*)(z + (size_t)row * 64);
#pragma unroll
    for (int ks = 0; ks < 2; ++ks) {
      float4 a = zr[ks * 8 + g * 2];
      float4 b = zr[ks * 8 + g * 2 + 1];
      s16x8 hh;
      hh[0] = (short)bf16_rne(__float_as_uint(a.x));
      hh[1] = (short)bf16_rne(__float_as_uint(a.y));
      hh[2] = (short)bf16_rne(__float_as_uint(a.z));
      hh[3] = (short)bf16_rne(__float_as_uint(a.w));
      hh[4] = (short)bf16_rne(__float_as_uint(b.x));
      hh[5] = (short)bf16_rne(__float_as_uint(b.y));
      hh[6] = (short)bf16_rne(__float_as_uint(b.z));
      hh[7] = (short)bf16_rne(__float_as_uint(b.w));
      zh[rt][ks] = hh;
    }
  }

  // packed-key top-3 per row-tile: key = (float_bits(m) & ~0x3FF) | code_idx
  unsigned q1[4] = {~0u, ~0u, ~0u, ~0u};
  unsigned q2[4] = {~0u, ~0u, ~0u, ~0u};
  unsigned q3[4] = {~0u, ~0u, ~0u, ~0u};

  const int aoff = ln16 * ROWB + g * 16;      // A-frag byte offset within code rows

  for (int p = 0; p < NPHASE; ++p) {
    __syncthreads();   // previous phase fully consumed
    {
      const float4* csrc = (const float4*)(ws + WS_CHUNK_OFF + (size_t)p * PH_CBYTES);
      float4* dst = (float4*)sblob;
#pragma unroll
      for (int i = 0; i < 9; ++i)            // 9*256*16B = 36864B exactly
        dst[t + 256 * i] = csrc[t + 256 * i];
      if (t < 64)                            // 64*16B = 1024B of norms
        ((float4*)(sblob + LDS_NRM_OFF))[t] =
            ((const float4*)(ws + WS_CHUNK_OFF + CODES_BYTES + (size_t)p * 1024))[t];
    }
    __syncthreads();

#pragma unroll 2
    for (int tl = 0; tl < 16; tl += 2) {
      // two code-tiles (32 codes) per iteration
      const char* abA = sblob + tl * (16 * ROWB) + aoff;
      const char* abB = abA + 16 * ROWB;
      s16x8 eA0 = *(const s16x8*)(abA);
      s16x8 eA1 = *(const s16x8*)(abA + 64);
      s16x8 eB0 = *(const s16x8*)(abB);
      s16x8 eB1 = *(const s16x8*)(abB + 64);
      f32x4 nrA = *(const f32x4*)(sblob + LDS_NRM_OFF + tl * 64 + (g << 4));
      f32x4 nrB = *(const f32x4*)(sblob + LDS_NRM_OFF + (tl + 1) * 64 + (g << 4));

      // acc init = biased norm; codes are -2x, so acc ends as m = nrm+MBIAS-2*dot
      f32x4 aA0 = nrA, aA1 = nrA, aA2 = nrA, aA3 = nrA;
      f32x4 aB0 = nrB, aB1 = nrB, aB2 = nrB, aB3 = nrB;
      aA0 = __builtin_amdgcn_mfma_f32_16x16x32_bf16(eA0, zh[0][0], aA0, 0, 0, 0);
      aA1 = __builtin_amdgcn_mfma_f32_16x16x32_bf16(eA0, zh[1][0], aA1, 0, 0, 0);
      aA2 = __builtin_amdgcn_mfma_f32_16x16x32_bf16(eA0, zh[2][0], aA2, 0, 0, 0);
      aA3 = __builtin_amdgcn_mfma_f32_16x16x32_bf16(eA0, zh[3][0], aA3, 0, 0, 0);
      aB0 = __builtin_amdgcn_mfma_f32_16x16x32_bf16(eB0, zh[0][0], aB0, 0, 0, 0);
      aB1 = __builtin_amdgcn_mfma_f32_16x16x32_bf16(eB0, zh[1][0], aB1, 0, 0, 0);
      aB2 = __builtin_amdgcn_mfma_f32_16x16x32_bf16(eB0, zh[2][0], aB2, 0, 0, 0);
      aB3 = __builtin_amdgcn_mfma_f32_16x16x32_bf16(eB0, zh[3][0], aB3, 0, 0, 0);
      aA0 = __builtin_amdgcn_mfma_f32_16x16x32_bf16(eA1, zh[0][1], aA0, 0, 0, 0);
      aA1 = __builtin_amdgcn_mfma_f32_16x16x32_bf16(eA1, zh[1][1], aA1, 0, 0, 0);
      aA2 = __builtin_amdgcn_mfma_f32_16x16x32_bf16(eA1, zh[2][1], aA2, 0, 0, 0);
      aA3 = __builtin_amdgcn_mfma_f32_16x16x32_bf16(eA1, zh[3][1], aA3, 0, 0, 0);
      aB0 = __builtin_amdgcn_mfma_f32_16x16x32_bf16(eB1, zh[0][1], aB0, 0, 0, 0);
      aB1 = __builtin_amdgcn_mfma_f32_16x16x32_bf16(eB1, zh[1][1], aB1, 0, 0, 0);
      aB2 = __builtin_amdgcn_mfma_f32_16x16x32_bf16(eB1, zh[2][1], aB2, 0, 0, 0);
      aB3 = __builtin_amdgcn_mfma_f32_16x16x32_bf16(eB1, zh[3][1], aB3, 0, 0, 0);

      const unsigned kbA = (unsigned)(p * PH_CODES + (tl << 4) + (g << 2));
      const unsigned kbB = kbA + 16;
#define UPDP(AC, KB, RT, R) {                                                 \
        unsigned key = (__float_as_uint(AC##RT[R]) & 0xFFFFFC00u) | (KB + R); \
        unsigned t1 = umax_(q1[RT], key); q1[RT] = umin_(q1[RT], key);        \
        unsigned t2 = umax_(q2[RT], t1);  q2[RT] = umin_(q2[RT], t1);         \
        q3[RT] = umin_(q3[RT], t2); }
      UPDP(aA, kbA, 0, 0) UPDP(aA, kbA, 1, 0) UPDP(aA, kbA, 2, 0) UPDP(aA, kbA, 3, 0)
      UPDP(aB, kbB, 0, 0) UPDP(aB, kbB, 1, 0) UPDP(aB, kbB, 2, 0) UPDP(aB, kbB, 3, 0)
      UPDP(aA, kbA, 0, 1) UPDP(aA, kbA, 1, 1) UPDP(aA, kbA, 2, 1) UPDP(aA, kbA, 3, 1)
      UPDP(aB, kbB, 0, 1) UPDP(aB, kbB, 1, 1) UPDP(aB, kbB, 2, 1) UPDP(aB, kbB, 3, 1)
      UPDP(aA, kbA, 0, 2) UPDP(aA, kbA, 1, 2) UPDP(aA, kbA, 2, 2) UPDP(aA, kbA, 3, 2)
      UPDP(aB, kbB, 0, 2) UPDP(aB, kbB, 1, 2) UPDP(aB, kbB, 2, 2) UPDP(aB, kbB, 3, 2)
      UPDP(aA, kbA, 0, 3) UPDP(aA, kbA, 1, 3) UPDP(aA, kbA, 2, 3) UPDP(aA, kbA, 3, 3)
      UPDP(aB, kbB, 0, 3) UPDP(aB, kbB, 1, 3) UPDP(aB, kbB, 2, 3) UPDP(aB, kbB, 3, 3)
#undef UPDP
    }
  }

  __syncthreads();                    // all waves done reading sblob codes
  int*   sk  = (int*)sblob;           // [256] overlaid
  float* red = (float*)(sblob + 1024);// [256] overlaid

  const float4* cb4 = (const float4*)cb;
  const float4* z4g = (const float4*)z;

#pragma unroll
  for (int rt = 0; rt < 4; ++rt) {
    unsigned a1 = q1[rt], a2 = q2[rt], a3 = q3[rt];
    // merge sorted triples across the 4 k-groups (lanes xor 16, 32)
#pragma unroll
    for (int dx = 16; dx <= 32; dx <<= 1) {
      unsigned b1 = (unsigned)__shfl_xor((int)a1, dx);
      unsigned b2 = (unsigned)__shfl_xor((int)a2, dx);
      unsigned b3 = (unsigned)__shfl_xor((int)a3, dx);
      unsigned x  = umax_(a1, b1);
      a1 = umin_(a1, b1);
      unsigned y  = umin_(a2, b2);
      unsigned zz = umax_(a2, b2);
      unsigned w3 = umin_(a3, b3);
      a2 = umin_(x, y);
      a3 = umin_(umax_(x, y), umin_(zz, w3));
    }
    int   i1 = (int)(a1 & 1023u), i2 = (int)(a2 & 1023u);
    float f1 = __uint_as_float(a1 & 0xFFFFFC00u);
    float f2 = __uint_as_float(a2 & 0xFFFFFC00u);
    float f3 = __uint_as_float(a3 & 0xFFFFFC00u);
    bool needFull = (f3 - f1) < GAP_Q;   // winner may lie outside {i1,i2}
    bool needPair = !needFull && ((f2 - f1) < GAP_Q);
    int  kstar = i1;

    if (g == 0) {
      int row = rowbase + rt * 16 + ln16;
      if (needPair) {
        float d1 = 0.f, d2 = 0.f;
        const float4* zr = z4g + (size_t)row * 16;
        const float4* c1 = cb4 + i1 * 16;
        const float4* c2 = cb4 + i2 * 16;
#pragma unroll
        for (int j = 0; j < 16; ++j) {
          float4 zv = zr[j], a = c1[j], b = c2[j];
          float e;
          e = zv.x - a.x; d1 = fmaf(e, e, d1);
          e = zv.y - a.y; d1 = fmaf(e, e, d1);
          e = zv.z - a.z; d1 = fmaf(e, e, d1);
          e = zv.w - a.w; d1 = fmaf(e, e, d1);
          e = zv.x - b.x; d2 = fmaf(e, e, d2);
          e = zv.y - b.y; d2 = fmaf(e, e, d2);
          e = zv.z - b.z; d2 = fmaf(e, e, d2);
          e = zv.w - b.w; d2 = fmaf(e, e, d2);
        }
        if (d2 < d1 || (d2 == d1 && i2 < i1)) kstar = i2;
      }
      if (!needFull) {
        sk[w * 64 + rt * 16 + ln16] = kstar;
        atomicAdd(&counts[kstar], 1u);
      }
    }

    // wave-cooperative exact full rescan for flagged rows (rare)
    unsigned long long fullmask = __ballot(needFull && g == 0);
    while (fullmask) {
      int src = __ffsll(fullmask) - 1;
      fullmask &= fullmask - 1;
      int lrow = w * 64 + rt * 16 + src;
      int row  = blockIdx.x * BLK_ROWS + lrow;
      const float4* zr = z4g + (size_t)row * 16;
      float bv = 3.4e38f; int bi = 0;
      for (int c16 = 0; c16 < 16; ++c16) {
        int code = c16 * 64 + lane;
        const float4* cr = cb4 + code * 16;
        float d = 0.f;
#pragma unroll
        for (int j = 0; j < 16; ++j) {
          float4 zv = zr[j], cv = cr[j];
          float e;
          e = zv.x - cv.x; d = fmaf(e, e, d);
          e = zv.y - cv.y; d = fmaf(e, e, d);
          e = zv.z - cv.z; d = fmaf(e, e, d);
          e = zv.w - cv.w; d = fmaf(e, e, d);
        }
        if (d < bv) { bv = d; bi = code; }
      }
#pragma unroll
      for (int dx = 1; dx < 64; dx <<= 1) {
        float ov = __shfl_xor(bv, dx); int oi = __shfl_xor(bi, dx);
        if (ov < bv || (ov == bv && oi < bi)) { bv = ov; bi = oi; }
      }
      if (lane == 0) { sk[lrow] = bi; atomicAdd(&counts[bi], 1u); }
    }
  }

  __syncthreads();

  // ---- cooperative z_q write + exact loss ----
  float lpart = 0.f;
  const int base4 = blockIdx.x * (BLK_ROWS * 16);
  float4* out4 = (float4*)zq;
#pragma unroll
  for (int i = 0; i < 16; ++i) {
    int idx = t + 256 * i;            // [0, 4096)
    int row = idx >> 4, c4 = idx & 15;
    int kk = sk[row];
    float4 cv = cb4[kk * 16 + c4];
    float4 zv = z4g[base4 + idx];
    float e;
    e = zv.x - cv.x; lpart = fmaf(e, e, lpart);
    e = zv.y - cv.y; lpart = fmaf(e, e, lpart);
    e = zv.z - cv.z; lpart = fmaf(e, e, lpart);
    e = zv.w - cv.w; lpart = fmaf(e, e, lpart);
    out4[base4 + idx] = cv;
  }
  red[t] = lpart;
  __syncthreads();
#pragma unroll
  for (int s = 128; s > 0; s >>= 1) {
    if (t < s) red[t] += red[t + s];
    __syncthreads();
  }
  if (t == 0) block_loss[blockIdx.x] = red[0];
}

// ---------------- finalize -------------
__global__ __launch_bounds__(1024) void vq_finalize(const unsigned int* __restrict__ counts,
                                                    const float* __restrict__ block_loss,
                                                    float* __restrict__ out, int nb) {
  __shared__ float sh[1024];
  __shared__ float sl[1024];
  const int t = threadIdx.x;
  float c = (float)counts[t];
  float p = c * (1.0f / (float)NROWS);
  sh[t] = p * logf(p + 1e-10f);
  float bl = (t < nb) ? block_loss[t] : 0.f;
  sl[t] = bl;
  __syncthreads();
#pragma unroll
  for (int s = 512; s > 0; s >>= 1) {
    if (t < s) { sh[t] += sh[t + s]; sl[t] += sl[t + s]; }
    __syncthreads();
  }
  if (t == 0) {
    out[NELEM]     = 1.25f * sl[0] / (float)NELEM;
    out[NELEM + 1] = expf(-sh[0]);
  }
}

// ---------------- fallback (small ws): fp32 kernel -------------
#define DOT4(acc, a, e) \
  acc = fmaf((a).x, (e).x, fmaf((a).y, (e).y, fmaf((a).z, (e).z, fmaf((a).w, (e).w, (acc)))))
#define SQD4(acc, a, e) { \
  float _dx = (e).x - (a).x, _dy = (e).y - (a).y, _dz = (e).z - (a).z, _dw = (e).w - (a).w; \
  acc = fmaf(_dx, _dx, fmaf(_dy, _dy, fmaf(_dz, _dz, fmaf(_dw, _dw, (acc))))); }

__global__ __launch_bounds__(256) void vq_norms_fb(const float* __restrict__ cb,
                                                   float* __restrict__ norms) {
  int k = blockIdx.x * blockDim.x + threadIdx.x;
  if (k >= K) return;
  const float4* e4 = (const float4*)(cb + (k << 6));
  float a0 = 0.f, a1 = 0.f, a2 = 0.f, a3 = 0.f;
#pragma unroll
  for (int j = 0; j < 16; j += 4) {
    float4 e;
    e = e4[j + 0]; DOT4(a0, e, e);
    e = e4[j + 1]; DOT4(a1, e, e);
    e = e4[j + 2]; DOT4(a2, e, e);
    e = e4[j + 3]; DOT4(a3, e, e);
  }
  norms[k] = (a0 + a1) + (a2 + a3);
}

__global__ __launch_bounds__(256) void vq_main_fb(const float* __restrict__ z,
                                                  const float* __restrict__ cb,
                                                  const float* __restrict__ norms,
                                                  float* __restrict__ zq,
                                                  unsigned int* __restrict__ counts,
                                                  float* __restrict__ block_loss) {
  const int tid = threadIdx.x;
  const int row = blockIdx.x * 256 + tid;
  const float4* zr4 = (const float4*)(z + (size_t)row * D);
  float4 zr[16];
#pragma unroll
  for (int j = 0; j < 16; ++j) zr[j] = zr4[j];
  float best = 3.4e38f;
  int   bidx = 0;
  for (int k = 0; k < K; k += 2) {
    const float4* e0 = (const float4*)(cb + (k << 6));
    const float4* e1 = e0 + 16;
    float a0 = 0.f, a1 = 0.f, a2 = 0.f, a3 = 0.f;
    float b0 = 0.f, b1 = 0.f, b2 = 0.f, b3 = 0.f;
#pragma unroll
    for (int j = 0; j < 16; j += 4) {
      float4 tt;
      tt = e0[j + 0]; DOT4(a0, zr[j + 0], tt);
      tt = e1[j + 0]; DOT4(b0, zr[j + 0], tt);
      tt = e0[j + 1]; DOT4(a1, zr[j + 1], tt);
      tt = e1[j + 1]; DOT4(b1, zr[j + 1], tt);
      tt = e0[j + 2]; DOT4(a2, zr[j + 2], tt);
      tt = e1[j + 2]; DOT4(b2, zr[j + 2], tt);
      tt = e0[j + 3]; DOT4(a3, zr[j + 3], tt);
      tt = e1[j + 3]; DOT4(b3, zr[j + 3], tt);
    }
    float d0 = (a0 + a1) + (a2 + a3);
    float d1 = (b0 + b1) + (b2 + b3);
    float m0 = fmaf(-2.f, d0, norms[k]);
    float m1 = fmaf(-2.f, d1, norms[k + 1]);
    if (m0 < best) { best = m0; bidx = k; }
    if (m1 < best) { best = m1; bidx = k + 1; }
  }
  const float4* eb4 = (const float4*)(cb + ((size_t)bidx << 6));
  float4* o4 = (float4*)(zq + (size_t)row * D);
  float l0 = 0.f, l1 = 0.f, l2 = 0.f, l3 = 0.f;
#pragma unroll
  for (int j = 0; j < 16; j += 4) {
    float4 e;
    e = eb4[j + 0]; o4[j + 0] = e; SQD4(l0, zr[j + 0], e);
    e = eb4[j + 1]; o4[j + 1] = e; SQD4(l1, zr[j + 1], e);
    e = eb4[j + 2]; o4[j + 2] = e; SQD4(l2, zr[j + 2], e);
    e = eb4[j + 3]; o4[j + 3] = e; SQD4(l3, zr[j + 3], e);
  }
  float row_loss = (l0 + l1) + (l2 + l3);
  atomicAdd(&counts[bidx], 1u);
  __shared__ float redf[256];
  redf[tid] = row_loss;
  __syncthreads();
#pragma unroll
  for (int s = 128; s > 0; s >>= 1) {
    if (tid < s) redf[tid] += redf[tid + s];
    __syncthreads();
  }
  if (tid == 0) block_loss[blockIdx.x] = redf[0];
}

// ---------------- launch -------------
extern "C" void kernel_launch(void* const* d_in, const int* in_sizes, int n_in,
                              void* d_out, int out_size, void* d_ws, size_t ws_size,
                              hipStream_t stream) {
  const float* z  = (const float*)d_in[0];
  const float* cb = (const float*)d_in[1];
  float* out = (float*)d_out;

  unsigned int* counts     = (unsigned int*)d_ws;
  float*        block_loss = (float*)((char*)d_ws + 4096);

  hipMemsetAsync(d_ws, 0, 4096, stream);   // zero counts

  if (ws_size >= WS_MAIN_NEED) {
    vq_prep<<<dim3(4), dim3(256), 0, stream>>>(cb, (char*)d_ws);
    vq_mfma<<<dim3(NBLOCKS), dim3(256), 0, stream>>>(z, cb, (const char*)d_ws,
                                                     out, counts, block_loss);
    vq_finalize<<<dim3(1), dim3(1024), 0, stream>>>(counts, block_loss, out, NBLOCKS);
  } else {
    float* norms = (float*)((char*)d_ws + 12288);
    vq_norms_fb<<<dim3(4), dim3(256), 0, stream>>>(cb, norms);
    vq_main_fb<<<dim3(NROWS / 256), dim3(256), 0, stream>>>(z, cb, norms,
                                                            out, counts, block_loss);
    vq_finalize<<<dim3(1), dim3(1024), 0, stream>>>(counts, block_loss, out, 1024);
  }
}

// Round 11
// 211.661 us; speedup vs baseline: 1.8825x; 1.7380x over previous
//
#include <hip/hip_runtime.h>
#include <math.h>

#define NROWS   (64 * 4096)                 // 262144 rows
#define D       64
#define K       1024
#define NELEM   ((size_t)NROWS * (size_t)D) // 16777216

// ---- MFMA-path geometry: EXACT R3 (best measured: 200us), hi+lo screening ----
#define CHUNK_CODES 128
#define ROWB        144                       // padded code row bytes
#define CBH_BYTES   (CHUNK_CODES * ROWB)      // 18432
#define REC_BYTES   (CBH_BYTES * 2 + 512)     // hi + lo + 128 biased norms = 37376
#define NCHUNK      (K / CHUNK_CODES)         // 8
#define WS_CHUNK_OFF 16384
#define WS_MAIN_NEED (WS_CHUNK_OFF + NCHUNK * REC_BYTES)   // 315392
#define BLK_ROWS    128                       // rows per block (4 waves x 32)
#define NBLOCKS     (NROWS / BLK_ROWS)        // 2048

#define MBIAS  256.0f   // m = dist^2 - ||z||^2 + 256 > 0 (chi2(64) tail at 256 ~ 0)
// hi/lo screen err ~1e-3; key quantization 0.03; GAP 0.25 = ~8x margin.
#define GAP_Q  0.25f

typedef float  f32x4  __attribute__((ext_vector_type(4)));
typedef short  s16x8  __attribute__((ext_vector_type(8)));

// ws layout (main path, bytes):
// [0,4096)       uint counts[1024]   (zeroed per call)
// [4096,12288)   float block_loss[2048]
// [16384,+8*37376) chunk records: {hi(-2x) 128x144B | lo(-2x) 128x144B | nrm+MBIAS 128xf32}
// fallback path: [12288,16384) float norms[1024]

static __device__ inline unsigned bf16_rne(unsigned u) {
  return (u + 0x7FFFu + ((u >> 16) & 1u)) >> 16;
}
static __device__ inline unsigned umin_(unsigned a, unsigned b) { return a < b ? a : b; }
static __device__ inline unsigned umax_(unsigned a, unsigned b) { return a > b ? a : b; }

// ---------------- prep: codebook -> bf16 hi/lo (-2x prescaled) + biased norms -------------
__global__ __launch_bounds__(256) void vq_prep(const float* __restrict__ cb,
                                               char* __restrict__ ws) {
  int k = blockIdx.x * 256 + threadIdx.x;
  if (k >= K) return;
  int chunk = k >> 7, cc = k & 127;
  char* rec = ws + WS_CHUNK_OFF + chunk * REC_BYTES;
  unsigned short* hrow = (unsigned short*)(rec + cc * ROWB);
  unsigned short* lrow = (unsigned short*)(rec + CBH_BYTES + cc * ROWB);
  const float* src = cb + (k << 6);
  float nrm = 0.f;
  for (int j = 0; j < 64; j += 2) {
    float x0 = src[j], x1 = src[j + 1];
    nrm = fmaf(x0, x0, fmaf(x1, x1, nrm));
    // hi = bf16(x); lo = bf16(x - hi). Store both prescaled by -2 (exact in bf16).
    unsigned h0 = bf16_rne(__float_as_uint(x0));
    unsigned h1 = bf16_rne(__float_as_uint(x1));
    float hf0 = __uint_as_float(h0 << 16), hf1 = __uint_as_float(h1 << 16);
    unsigned hs0 = bf16_rne(__float_as_uint(-2.f * x0));        // == -2*hi
    unsigned hs1 = bf16_rne(__float_as_uint(-2.f * x1));
    unsigned ls0 = bf16_rne(__float_as_uint(-2.f * (x0 - hf0))); // == -2*lo
    unsigned ls1 = bf16_rne(__float_as_uint(-2.f * (x1 - hf1)));
    *(unsigned*)(hrow + j) = hs0 | (hs1 << 16);
    *(unsigned*)(lrow + j) = ls0 | (ls1 << 16);
  }
  *(float*)(rec + 2 * CBH_BYTES + cc * 4) = nrm + MBIAS;
}

// ---------------- main MFMA kernel: R3 schedule + packed-key tracker -------------
__global__ __launch_bounds__(256, 4) void vq_mfma(const float* __restrict__ z,
                                                  const float* __restrict__ cb,
                                                  const char* __restrict__ ws,
                                                  float* __restrict__ zq,
                                                  unsigned int* __restrict__ counts,
                                                  float* __restrict__ block_loss) {
  __shared__ __align__(16) char sblob[REC_BYTES];   // 37376 B; sk/red overlaid post-loop

  const int t    = threadIdx.x;
  const int w    = t >> 6;          // wave 0..3
  const int lane = t & 63;
  const int g    = lane >> 4;       // k-group 0..3
  const int ln16 = lane & 15;

  // ---- z rows (2 row-tiles x 16 rows) -> bf16 hi/lo B-frags (unscaled) ----
  const int rowbase = blockIdx.x * BLK_ROWS + w * 32;
  s16x8 zh[2][2], zl[2][2];
#pragma unroll
  for (int rt = 0; rt < 2; ++rt) {
    int row = rowbase + rt * 16 + ln16;
    const float4* zr = (const float4*)(z + (size_t)row * 64);
#pragma unroll
    for (int ks = 0; ks < 2; ++ks) {
      float4 a = zr[ks * 8 + g * 2];
      float4 b = zr[ks * 8 + g * 2 + 1];
      float xs[8] = {a.x, a.y, a.z, a.w, b.x, b.y, b.z, b.w};
      s16x8 hh, ll;
#pragma unroll
      for (int j = 0; j < 8; ++j) {
        unsigned hb = bf16_rne(__float_as_uint(xs[j]));
        float hf = __uint_as_float(hb << 16);
        unsigned lb = bf16_rne(__float_as_uint(xs[j] - hf));
        hh[j] = (short)hb; ll[j] = (short)lb;
      }
      zh[rt][ks] = hh; zl[rt][ks] = ll;
    }
  }

  // packed-key top-3 per row-tile: key = (float_bits(m) & ~0x3FF) | code_idx
  unsigned q1a = ~0u, q2a = ~0u, q3a = ~0u;
  unsigned q1b = ~0u, q2b = ~0u, q3b = ~0u;

  const int aoff = ln16 * ROWB + g * 16;

  for (int c = 0; c < NCHUNK; ++c) {
    __syncthreads();
    {
      const float4* src = (const float4*)(ws + WS_CHUNK_OFF + (size_t)c * REC_BYTES);
      float4* dst = (float4*)sblob;
#pragma unroll
      for (int i = 0; i < 10; ++i) {
        int idx = t + 256 * i;
        if (idx < REC_BYTES / 16) dst[idx] = src[idx];
      }
    }
    __syncthreads();

#pragma unroll
    for (int tl = 0; tl < CHUNK_CODES / 16; ++tl) {
      const char* ab = sblob + tl * 16 * ROWB + aoff;
      s16x8 eh0 = *(const s16x8*)(ab);
      s16x8 eh1 = *(const s16x8*)(ab + 64);
      s16x8 el0 = *(const s16x8*)(ab + CBH_BYTES);
      s16x8 el1 = *(const s16x8*)(ab + CBH_BYTES + 64);
      f32x4 nr  = *(const f32x4*)(sblob + 2 * CBH_BYTES + tl * 64 + (g << 4));

      // acc init = biased norm; codes prescaled -2 -> acc = nrm+MBIAS-2(hh+lh+hl dots)
      f32x4 acc0 = nr, acc1 = nr;
      acc0 = __builtin_amdgcn_mfma_f32_16x16x32_bf16(eh0, zh[0][0], acc0, 0, 0, 0);
      acc1 = __builtin_amdgcn_mfma_f32_16x16x32_bf16(eh0, zh[1][0], acc1, 0, 0, 0);
      acc0 = __builtin_amdgcn_mfma_f32_16x16x32_bf16(eh1, zh[0][1], acc0, 0, 0, 0);
      acc1 = __builtin_amdgcn_mfma_f32_16x16x32_bf16(eh1, zh[1][1], acc1, 0, 0, 0);
      acc0 = __builtin_amdgcn_mfma_f32_16x16x32_bf16(el0, zh[0][0], acc0, 0, 0, 0);
      acc1 = __builtin_amdgcn_mfma_f32_16x16x32_bf16(el0, zh[1][0], acc1, 0, 0, 0);
      acc0 = __builtin_amdgcn_mfma_f32_16x16x32_bf16(el1, zh[0][1], acc0, 0, 0, 0);
      acc1 = __builtin_amdgcn_mfma_f32_16x16x32_bf16(el1, zh[1][1], acc1, 0, 0, 0);
      acc0 = __builtin_amdgcn_mfma_f32_16x16x32_bf16(eh0, zl[0][0], acc0, 0, 0, 0);
      acc1 = __builtin_amdgcn_mfma_f32_16x16x32_bf16(eh0, zl[1][0], acc1, 0, 0, 0);
      acc0 = __builtin_amdgcn_mfma_f32_16x16x32_bf16(eh1, zl[0][1], acc0, 0, 0, 0);
      acc1 = __builtin_amdgcn_mfma_f32_16x16x32_bf16(eh1, zl[1][1], acc1, 0, 0, 0);

      const unsigned kb = (unsigned)((c << 7) + (tl << 4) + (g << 2));
#define UPDP(S, AC, R) {                                                      \
        unsigned key = (__float_as_uint(AC[R]) & 0xFFFFFC00u) | (kb + R);     \
        unsigned t1 = umax_(q1##S, key); q1##S = umin_(q1##S, key);           \
        unsigned t2 = umax_(q2##S, t1);  q2##S = umin_(q2##S, t1);            \
        q3##S = umin_(q3##S, t2); }
      UPDP(a, acc0, 0) UPDP(a, acc0, 1) UPDP(a, acc0, 2) UPDP(a, acc0, 3)
      UPDP(b, acc1, 0) UPDP(b, acc1, 1) UPDP(b, acc1, 2) UPDP(b, acc1, 3)
#undef UPDP
    }
  }

  __syncthreads();                  // all waves done reading sblob codes
  int*   sk  = (int*)sblob;         // [128] overlaid
  float* red = (float*)(sblob + 512); // [256] overlaid

  const float4* cb4 = (const float4*)cb;
  const float4* z4g = (const float4*)z;

#pragma unroll
  for (int rt = 0; rt < 2; ++rt) {
    unsigned a1 = rt ? q1b : q1a;
    unsigned a2 = rt ? q2b : q2a;
    unsigned a3 = rt ? q3b : q3a;
    // merge sorted triples across the 4 k-groups (lanes xor 16, 32)
#pragma unroll
    for (int dx = 16; dx <= 32; dx <<= 1) {
      unsigned b1 = (unsigned)__shfl_xor((int)a1, dx);
      unsigned b2 = (unsigned)__shfl_xor((int)a2, dx);
      unsigned b3 = (unsigned)__shfl_xor((int)a3, dx);
      unsigned x  = umax_(a1, b1);
      a1 = umin_(a1, b1);
      unsigned y  = umin_(a2, b2);
      unsigned zz = umax_(a2, b2);
      unsigned w3 = umin_(a3, b3);
      a2 = umin_(x, y);
      a3 = umin_(umax_(x, y), umin_(zz, w3));
    }
    int   i1 = (int)(a1 & 1023u), i2 = (int)(a2 & 1023u);
    float f1 = __uint_as_float(a1 & 0xFFFFFC00u);
    float f2 = __uint_as_float(a2 & 0xFFFFFC00u);
    float f3 = __uint_as_float(a3 & 0xFFFFFC00u);
    bool needFull = (f3 - f1) < GAP_Q;
    bool needPair = !needFull && ((f2 - f1) < GAP_Q);
    int  kstar = i1;

    if (g == 0) {
      int row = rowbase + rt * 16 + ln16;
      if (needPair) {
        float d1 = 0.f, d2 = 0.f;
        const float4* zr = z4g + (size_t)row * 16;
        const float4* c1 = cb4 + i1 * 16;
        const float4* c2 = cb4 + i2 * 16;
#pragma unroll
        for (int j = 0; j < 16; ++j) {
          float4 zv = zr[j], a = c1[j], b = c2[j];
          float e;
          e = zv.x - a.x; d1 = fmaf(e, e, d1);
          e = zv.y - a.y; d1 = fmaf(e, e, d1);
          e = zv.z - a.z; d1 = fmaf(e, e, d1);
          e = zv.w - a.w; d1 = fmaf(e, e, d1);
          e = zv.x - b.x; d2 = fmaf(e, e, d2);
          e = zv.y - b.y; d2 = fmaf(e, e, d2);
          e = zv.z - b.z; d2 = fmaf(e, e, d2);
          e = zv.w - b.w; d2 = fmaf(e, e, d2);
        }
        if (d2 < d1 || (d2 == d1 && i2 < i1)) kstar = i2;
      }
      if (!needFull) {
        sk[w * 32 + rt * 16 + ln16] = kstar;
        atomicAdd(&counts[kstar], 1u);
      }
    }

    // wave-cooperative exact full rescan for flagged rows (rare)
    unsigned long long fullmask = __ballot(needFull && g == 0);
    while (fullmask) {
      int src = __ffsll(fullmask) - 1;
      fullmask &= fullmask - 1;
      int lrow = w * 32 + rt * 16 + src;
      int row  = blockIdx.x * BLK_ROWS + lrow;
      const float4* zr = z4g + (size_t)row * 16;
      float bv = 3.4e38f; int bi = 0;
      for (int c16 = 0; c16 < 16; ++c16) {
        int code = c16 * 64 + lane;
        const float4* cr = cb4 + code * 16;
        float d = 0.f;
#pragma unroll
        for (int j = 0; j < 16; ++j) {
          float4 zv = zr[j], cv = cr[j];
          float e;
          e = zv.x - cv.x; d = fmaf(e, e, d);
          e = zv.y - cv.y; d = fmaf(e, e, d);
          e = zv.z - cv.z; d = fmaf(e, e, d);
          e = zv.w - cv.w; d = fmaf(e, e, d);
        }
        if (d < bv) { bv = d; bi = code; }
      }
#pragma unroll
      for (int dx = 1; dx < 64; dx <<= 1) {
        float ov = __shfl_xor(bv, dx); int oi = __shfl_xor(bi, dx);
        if (ov < bv || (ov == bv && oi < bi)) { bv = ov; bi = oi; }
      }
      if (lane == 0) { sk[lrow] = bi; atomicAdd(&counts[bi], 1u); }
    }
  }

  __syncthreads();

  // ---- cooperative z_q write + exact loss ----
  float lpart = 0.f;
  const int base4 = blockIdx.x * (BLK_ROWS * 16);
  float4* out4 = (float4*)zq;
#pragma unroll
  for (int i = 0; i < 8; ++i) {
    int idx = t + 256 * i;            // [0, 2048)
    int row = idx >> 4, c4 = idx & 15;
    int kk = sk[row];
    float4 cv = cb4[kk * 16 + c4];
    float4 zv = z4g[base4 + idx];
    float e;
    e = zv.x - cv.x; lpart = fmaf(e, e, lpart);
    e = zv.y - cv.y; lpart = fmaf(e, e, lpart);
    e = zv.z - cv.z; lpart = fmaf(e, e, lpart);
    e = zv.w - cv.w; lpart = fmaf(e, e, lpart);
    out4[base4 + idx] = cv;
  }
  red[t] = lpart;
  __syncthreads();
#pragma unroll
  for (int s = 128; s > 0; s >>= 1) {
    if (t < s) red[t] += red[t + s];
    __syncthreads();
  }
  if (t == 0) block_loss[blockIdx.x] = red[0];
}

// ---------------- finalize -------------
__global__ __launch_bounds__(1024) void vq_finalize(const unsigned int* __restrict__ counts,
                                                    const float* __restrict__ block_loss,
                                                    float* __restrict__ out, int nb) {
  __shared__ float sh[1024];
  __shared__ float sl[1024];
  const int t = threadIdx.x;
  float c = (float)counts[t];
  float p = c * (1.0f / (float)NROWS);
  sh[t] = p * logf(p + 1e-10f);
  float bl = (t < nb) ? block_loss[t] : 0.f;
  if (t + 1024 < nb) bl += block_loss[t + 1024];
  sl[t] = bl;
  __syncthreads();
#pragma unroll
  for (int s = 512; s > 0; s >>= 1) {
    if (t < s) { sh[t] += sh[t + s]; sl[t] += sl[t + s]; }
    __syncthreads();
  }
  if (t == 0) {
    out[NELEM]     = 1.25f * sl[0] / (float)NELEM;
    out[NELEM + 1] = expf(-sh[0]);
  }
}

// ---------------- fallback (small ws): fp32 kernel -------------
#define DOT4(acc, a, e) \
  acc = fmaf((a).x, (e).x, fmaf((a).y, (e).y, fmaf((a).z, (e).z, fmaf((a).w, (e).w, (acc)))))
#define SQD4(acc, a, e) { \
  float _dx = (e).x - (a).x, _dy = (e).y - (a).y, _dz = (e).z - (a).z, _dw = (e).w - (a).w; \
  acc = fmaf(_dx, _dx, fmaf(_dy, _dy, fmaf(_dz, _dz, fmaf(_dw, _dw, (acc))))); }

__global__ __launch_bounds__(256) void vq_norms_fb(const float* __restrict__ cb,
                                                   float* __restrict__ norms) {
  int k = blockIdx.x * blockDim.x + threadIdx.x;
  if (k >= K) return;
  const float4* e4 = (const float4*)(cb + (k << 6));
  float a0 = 0.f, a1 = 0.f, a2 = 0.f, a3 = 0.f;
#pragma unroll
  for (int j = 0; j < 16; j += 4) {
    float4 e;
    e = e4[j + 0]; DOT4(a0, e, e);
    e = e4[j + 1]; DOT4(a1, e, e);
    e = e4[j + 2]; DOT4(a2, e, e);
    e = e4[j + 3]; DOT4(a3, e, e);
  }
  norms[k] = (a0 + a1) + (a2 + a3);
}

__global__ __launch_bounds__(256) void vq_main_fb(const float* __restrict__ z,
                                                  const float* __restrict__ cb,
                                                  const float* __restrict__ norms,
                                                  float* __restrict__ zq,
                                                  unsigned int* __restrict__ counts,
                                                  float* __restrict__ block_loss) {
  const int tid = threadIdx.x;
  const int row = blockIdx.x * 256 + tid;
  const float4* zr4 = (const float4*)(z + (size_t)row * D);
  float4 zr[16];
#pragma unroll
  for (int j = 0; j < 16; ++j) zr[j] = zr4[j];
  float best = 3.4e38f;
  int   bidx = 0;
  for (int k = 0; k < K; k += 2) {
    const float4* e0 = (const float4*)(cb + (k << 6));
    const float4* e1 = e0 + 16;
    float a0 = 0.f, a1 = 0.f, a2 = 0.f, a3 = 0.f;
    float b0 = 0.f, b1 = 0.f, b2 = 0.f, b3 = 0.f;
#pragma unroll
    for (int j = 0; j < 16; j += 4) {
      float4 tt;
      tt = e0[j + 0]; DOT4(a0, zr[j + 0], tt);
      tt = e1[j + 0]; DOT4(b0, zr[j + 0], tt);
      tt = e0[j + 1]; DOT4(a1, zr[j + 1], tt);
      tt = e1[j + 1]; DOT4(b1, zr[j + 1], tt);
      tt = e0[j + 2]; DOT4(a2, zr[j + 2], tt);
      tt = e1[j + 2]; DOT4(b2, zr[j + 2], tt);
      tt = e0[j + 3]; DOT4(a3, zr[j + 3], tt);
      tt = e1[j + 3]; DOT4(b3, zr[j + 3], tt);
    }
    float d0 = (a0 + a1) + (a2 + a3);
    float d1 = (b0 + b1) + (b2 + b3);
    float m0 = fmaf(-2.f, d0, norms[k]);
    float m1 = fmaf(-2.f, d1, norms[k + 1]);
    if (m0 < best) { best = m0; bidx = k; }
    if (m1 < best) { best = m1; bidx = k + 1; }
  }
  const float4* eb4 = (const float4*)(cb + ((size_t)bidx << 6));
  float4* o4 = (float4*)(zq + (size_t)row * D);
  float l0 = 0.f, l1 = 0.f, l2 = 0.f, l3 = 0.f;
#pragma unroll
  for (int j = 0; j < 16; j += 4) {
    float4 e;
    e = eb4[j + 0]; o4[j + 0] = e; SQD4(l0, zr[j + 0], e);
    e = eb4[j + 1]; o4[j + 1] = e; SQD4(l1, zr[j + 1], e);
    e = eb4[j + 2]; o4[j + 2] = e; SQD4(l2, zr[j + 2], e);
    e = eb4[j + 3]; o4[j + 3] = e; SQD4(l3, zr[j + 3], e);
  }
  float row_loss = (l0 + l1) + (l2 + l3);
  atomicAdd(&counts[bidx], 1u);
  __shared__ float redf[256];
  redf[tid] = row_loss;
  __syncthreads();
#pragma unroll
  for (int s = 128; s > 0; s >>= 1) {
    if (tid < s) redf[tid] += redf[tid + s];
    __syncthreads();
  }
  if (tid == 0) block_loss[blockIdx.x] = redf[0];
}

// ---------------- launch -------------
extern "C" void kernel_launch(void* const* d_in, const int* in_sizes, int n_in,
                              void* d_out, int out_size, void* d_ws, size_t ws_size,
                              hipStream_t stream) {
  const float* z  = (const float*)d_in[0];
  const float* cb = (const float*)d_in[1];
  float* out = (float*)d_out;

  unsigned int* counts     = (unsigned int*)d_ws;
  float*        block_loss = (float*)((char*)d_ws + 4096);

  hipMemsetAsync(d_ws, 0, 4096, stream);   // zero counts

  if (ws_size >= WS_MAIN_NEED) {
    vq_prep<<<dim3(4), dim3(256), 0, stream>>>(cb, (char*)d_ws);
    vq_mfma<<<dim3(NBLOCKS), dim3(256), 0, stream>>>(z, cb, (const char*)d_ws,
                                                     out, counts, block_loss);
    vq_finalize<<<dim3(1), dim3(1024), 0, stream>>>(counts, block_loss, out, NBLOCKS);
  } else {
    float* norms = (float*)((char*)d_ws + 12288);
    vq_norms_fb<<<dim3(4), dim3(256), 0, stream>>>(cb, norms);
    vq_main_fb<<<dim3(NROWS / 256), dim3(256), 0, stream>>>(z, cb, norms,
                                                            out, counts, block_loss);
    vq_finalize<<<dim3(1), dim3(1024), 0, stream>>>(counts, block_loss, out, 1024);
  }
}